// Round 11
// baseline (320.185 us; speedup 1.0000x reference)
//
#include <hip/hip_runtime.h>

// Problem constants
constexpr int kE = 65536, kNTOT = 8192;

// ---------------- threefry2x32 (JAX-exact, 20 rounds) ----------------
__host__ __device__ __forceinline__ void tf_round(unsigned& x0, unsigned& x1, int r) {
  x0 += x1;
  x1 = (x1 << r) | (x1 >> (32 - r));
  x1 ^= x0;
}
__host__ __device__ __forceinline__ void tf2x32(unsigned k0, unsigned k1,
                                                unsigned& x0, unsigned& x1) {
  unsigned ks2 = k0 ^ k1 ^ 0x1BD11BDAu;
  x0 += k0; x1 += k1;
  tf_round(x0,x1,13); tf_round(x0,x1,15); tf_round(x0,x1,26); tf_round(x0,x1,6);
  x0 += k1; x1 += ks2 + 1u;
  tf_round(x0,x1,17); tf_round(x0,x1,29); tf_round(x0,x1,16); tf_round(x0,x1,24);
  x0 += ks2; x1 += k0 + 2u;
  tf_round(x0,x1,13); tf_round(x0,x1,15); tf_round(x0,x1,26); tf_round(x0,x1,6);
  x0 += k0; x1 += k1 + 3u;
  tf_round(x0,x1,17); tf_round(x0,x1,29); tf_round(x0,x1,16); tf_round(x0,x1,24);
  x0 += k1; x1 += ks2 + 4u;
  tf_round(x0,x1,13); tf_round(x0,x1,15); tf_round(x0,x1,26); tf_round(x0,x1,6);
  x0 += ks2; x1 += k0 + 5u;
}

// bits -> N(0,1), replicating jax.random.normal f32 path (partitionable threefry)
__device__ __forceinline__ float bits_to_normal(unsigned bits) {
  float f = __uint_as_float((bits >> 9) | 0x3f800000u) - 1.0f;  // [0,1)
  const float LO = -0.99999994f;
  float u = fmaf(f, 2.0f, LO);
  u = fmaxf(u, LO);
  float w = -log1pf(-u * u);
  float p;
  if (w < 5.0f) {
    w -= 2.5f;
    p = 2.81022636e-08f;
    p = fmaf(p, w, 3.43273939e-07f);
    p = fmaf(p, w, -3.5233877e-06f);
    p = fmaf(p, w, -4.39150654e-06f);
    p = fmaf(p, w, 0.00021858087f);
    p = fmaf(p, w, -0.00125372503f);
    p = fmaf(p, w, -0.00417768164f);
    p = fmaf(p, w, 0.246640727f);
    p = fmaf(p, w, 1.50140941f);
  } else {
    w = sqrtf(w) - 3.0f;
    p = -0.000200214257f;
    p = fmaf(p, w, 0.000100950558f);
    p = fmaf(p, w, 0.00134934322f);
    p = fmaf(p, w, -0.00367342844f);
    p = fmaf(p, w, 0.00573950773f);
    p = fmaf(p, w, -0.0076224613f);
    p = fmaf(p, w, 0.00943887047f);
    p = fmaf(p, w, 1.00167406f);
    p = fmaf(p, w, 2.83297682f);
  }
  return 1.41421356f * (p * u);
}

__device__ __forceinline__ float redmax32(float v) {
#pragma unroll
  for (int o = 16; o > 0; o >>= 1) v = fmaxf(v, __shfl_xor(v, o));
  return v;
}
__device__ __forceinline__ float redsum32(float v) {
#pragma unroll
  for (int o = 16; o > 0; o >>= 1) v += __shfl_xor(v, o);
  return v;
}

// ================= CSR build (multi-block) + agg zeroing =================
// hist counts into off[] (zeroed by memset); agg zeroed here for atomic accumulation.
__global__ __launch_bounds__(256) void hist_kern(const int* __restrict__ eiR,
                                                 const int* __restrict__ eiP,
                                                 int* __restrict__ offR,
                                                 int* __restrict__ offP,
                                                 float* __restrict__ aggz) {
  int i = blockIdx.x * 256 + threadIdx.x;  // 0..131071
  float4 z4 = make_float4(0.f, 0.f, 0.f, 0.f);
  float4* z = reinterpret_cast<float4*>(aggz) + i * 2;
  z[0] = z4; z[1] = z4;
  const int* ei = (i < kE) ? eiR : eiP;
  int* off = (i < kE) ? offR : offP;
  int e = i & (kE - 1);
  atomicAdd(&off[ei[kE + e]], 1);
}

// 2 blocks (one per graph): in-place exclusive scan of off[] (counts -> offsets)
__global__ __launch_bounds__(256) void scan_kern(int* __restrict__ offR,
                                                 int* __restrict__ offP) {
  int* off = blockIdx.x ? offP : offR;
  int t = threadIdx.x;
  int base = t * 32;
  int v[32];
#pragma unroll
  for (int i = 0; i < 32; ++i) v[i] = off[base + i];
  int sum = 0;
#pragma unroll
  for (int i = 0; i < 32; ++i) sum += v[i];
  int lane = t & 63, w = t >> 6;
  int incl = sum;
#pragma unroll
  for (int o = 1; o < 64; o <<= 1) {
    int y = __shfl_up(incl, o);
    if (lane >= o) incl += y;
  }
  __shared__ int wsum[4];
  if (lane == 63) wsum[w] = incl;
  __syncthreads();
  int woff = 0;
#pragma unroll
  for (int i = 0; i < 4; ++i) if (i < w) woff += wsum[i];
  int running = woff + incl - sum;
#pragma unroll
  for (int i = 0; i < 32; ++i) {
    off[base + i] = running;
    running += v[i];
  }
}

__global__ __launch_bounds__(256) void scatter_kern(
    const int* __restrict__ eiR, const int* __restrict__ eiP,
    int* __restrict__ offR, int* __restrict__ offP,
    int* __restrict__ permR, int* __restrict__ permP,
    int* __restrict__ srcsR, int* __restrict__ srcsP,
    int* __restrict__ dstsR, int* __restrict__ dstsP) {
  int i = blockIdx.x * 256 + threadIdx.x;
  const int* ei = (i < kE) ? eiR : eiP;
  int* off = (i < kE) ? offR : offP;
  int* perm = (i < kE) ? permR : permP;
  int* srcs = (i < kE) ? srcsR : srcsP;
  int* dsts = (i < kE) ? dstsR : dstsP;
  int e = i & (kE - 1);
  int dst = ei[kE + e];
  int pos = atomicAdd(&off[dst], 1);
  perm[pos] = e;
  srcs[pos] = ei[e];
  dsts[pos] = dst;
}

// ====== msg GEMM (gnn1) + fused segment-reduce agg  |  blocks>=2048: efwe precompute ===
// efwe[i] = ef[perm[i]] @ We2 (CSR-sorted, no relu) — iteration-invariant gnn2 edge part.
template <int KX>
__global__ __launch_bounds__(256) void msg_gemm(
    const float* __restrict__ xR, const float* __restrict__ efR,
    const int* __restrict__ srcsR, const int* __restrict__ permR,
    const int* __restrict__ dstsR, float* __restrict__ aggR,
    const float* __restrict__ xP, const float* __restrict__ efP,
    const int* __restrict__ srcsP, const int* __restrict__ permP,
    const int* __restrict__ dstsP, float* __restrict__ aggP,
    const float* __restrict__ Wm, const float* __restrict__ We,
    const float* __restrict__ We2, float* __restrict__ efweR, float* __restrict__ efweP) {
  constexpr int KT = KX + 16;
  constexpr int SA_ROWS = (KT > 64) ? KT : 64;
  __shared__ float sA[SA_ROWS][68];
  __shared__ float sW[KT][68];
  __shared__ int sDst[64];
  int t = threadIdx.x;
  if (blockIdx.x >= 2048) {
    // ---- efwe precompute path: 64 sorted edges x 64 cols, K=16 ----
    int tile = blockIdx.x - 2048;
    bool isP2 = tile >= 1024;
    const float* ef2 = isP2 ? efP : efR;
    const int* perm2 = isP2 ? permP : permR;
    float* ew = isP2 ? efweP : efweR;
    int i0 = (tile & 1023) * 64;
    {
      int q = t * 4;  // stage We2 (16x64)
      int k = q >> 6, j = q & 63;
      *reinterpret_cast<float4*>(&sW[k][j]) = *reinterpret_cast<const float4*>(We2 + q);
    }
    {
      int q = t * 4;  // gather ef rows (64 x 16), transposed into sA[k][r]
      int r = q >> 4, k = q & 15;
      float4 v = *reinterpret_cast<const float4*>(ef2 + (size_t)perm2[i0 + r] * 16 + k);
      sA[k + 0][r] = v.x; sA[k + 1][r] = v.y; sA[k + 2][r] = v.z; sA[k + 3][r] = v.w;
    }
    __syncthreads();
    int tn = (t & 15) * 4, tj = (t >> 4) * 4;
    float acc[4][4] = {};
#pragma unroll
    for (int k = 0; k < 16; ++k) {
      float4 a = *reinterpret_cast<const float4*>(&sA[k][tn]);
      float4 b = *reinterpret_cast<const float4*>(&sW[k][tj]);
      acc[0][0] = fmaf(a.x, b.x, acc[0][0]); acc[0][1] = fmaf(a.x, b.y, acc[0][1]);
      acc[0][2] = fmaf(a.x, b.z, acc[0][2]); acc[0][3] = fmaf(a.x, b.w, acc[0][3]);
      acc[1][0] = fmaf(a.y, b.x, acc[1][0]); acc[1][1] = fmaf(a.y, b.y, acc[1][1]);
      acc[1][2] = fmaf(a.y, b.z, acc[1][2]); acc[1][3] = fmaf(a.y, b.w, acc[1][3]);
      acc[2][0] = fmaf(a.z, b.x, acc[2][0]); acc[2][1] = fmaf(a.z, b.y, acc[2][1]);
      acc[2][2] = fmaf(a.z, b.z, acc[2][2]); acc[2][3] = fmaf(a.z, b.w, acc[2][3]);
      acc[3][0] = fmaf(a.w, b.x, acc[3][0]); acc[3][1] = fmaf(a.w, b.y, acc[3][1]);
      acc[3][2] = fmaf(a.w, b.z, acc[3][2]); acc[3][3] = fmaf(a.w, b.w, acc[3][3]);
    }
#pragma unroll
    for (int i = 0; i < 4; ++i) {
      float4 o = make_float4(acc[i][0], acc[i][1], acc[i][2], acc[i][3]);
      *reinterpret_cast<float4*>(&ew[(size_t)(i0 + tn + i) * 64 + tj]) = o;
    }
    return;
  }
  // ---- gnn1 msg GEMM path (verified R10) ----
  bool isP = blockIdx.x >= 1024;
  const float* x = isP ? xP : xR;
  const float* ef = isP ? efP : efR;
  const int* srcs = isP ? srcsP : srcsR;
  const int* perm = isP ? permP : permR;
  const int* dsts = isP ? dstsP : dstsR;
  float* agg = isP ? aggP : aggR;
  int i0 = (blockIdx.x & 1023) * 64;
#pragma unroll
  for (int idx = 0; idx < KT * 64 / 1024; ++idx) {
    int q = t * 4 + idx * 1024;
    int k = q >> 6, j = q & 63;
    const float* sp = (k < KX) ? (Wm + k * 64 + j) : (We + (k - KX) * 64 + j);
    float4 v = *reinterpret_cast<const float4*>(sp);
    *reinterpret_cast<float4*>(&sW[k][j]) = v;
  }
  if (t < 64) sDst[t] = dsts[i0 + t];
#pragma unroll
  for (int idx = 0; idx < KT * 64 / 1024; ++idx) {
    int q = t * 4 + idx * 1024;
    int r = q / KT;
    int k = q % KT;   // 4-aligned
    const float* rptr = (k < KX) ? (x + (size_t)srcs[i0 + r] * KX + k)
                                 : (ef + (size_t)perm[i0 + r] * 16 + (k - KX));
    float4 v = *reinterpret_cast<const float4*>(rptr);
    sA[k + 0][r] = v.x; sA[k + 1][r] = v.y; sA[k + 2][r] = v.z; sA[k + 3][r] = v.w;
  }
  __syncthreads();
  int tn = (t & 15) * 4;
  int tj = (t >> 4) * 4;
  float acc[4][4] = {};
#pragma unroll 8
  for (int k = 0; k < KT; ++k) {
    float4 a = *reinterpret_cast<const float4*>(&sA[k][tn]);
    float4 b = *reinterpret_cast<const float4*>(&sW[k][tj]);
    acc[0][0] = fmaf(a.x, b.x, acc[0][0]); acc[0][1] = fmaf(a.x, b.y, acc[0][1]);
    acc[0][2] = fmaf(a.x, b.z, acc[0][2]); acc[0][3] = fmaf(a.x, b.w, acc[0][3]);
    acc[1][0] = fmaf(a.y, b.x, acc[1][0]); acc[1][1] = fmaf(a.y, b.y, acc[1][1]);
    acc[1][2] = fmaf(a.y, b.z, acc[1][2]); acc[1][3] = fmaf(a.y, b.w, acc[1][3]);
    acc[2][0] = fmaf(a.z, b.x, acc[2][0]); acc[2][1] = fmaf(a.z, b.y, acc[2][1]);
    acc[2][2] = fmaf(a.z, b.z, acc[2][2]); acc[2][3] = fmaf(a.z, b.w, acc[2][3]);
    acc[3][0] = fmaf(a.w, b.x, acc[3][0]); acc[3][1] = fmaf(a.w, b.y, acc[3][1]);
    acc[3][2] = fmaf(a.w, b.z, acc[3][2]); acc[3][3] = fmaf(a.w, b.w, acc[3][3]);
  }
  __syncthreads();            // reuse sA as output tile [row][col]
#pragma unroll
  for (int i = 0; i < 4; ++i) {
    sA[tn + i][tj + 0] = fmaxf(acc[i][0], 0.f);
    sA[tn + i][tj + 1] = fmaxf(acc[i][1], 0.f);
    sA[tn + i][tj + 2] = fmaxf(acc[i][2], 0.f);
    sA[tn + i][tj + 3] = fmaxf(acc[i][3], 0.f);
  }
  __syncthreads();
  int col = t & 63;
  int r0l = (t >> 6) * 16;
  float run = 0.f;
  int rd = sDst[r0l];
#pragma unroll
  for (int r = 0; r < 16; ++r) {
    int d = sDst[r0l + r];
    if (d != rd) {
      unsafeAtomicAdd(&agg[(size_t)rd * 64 + col], run);
      run = 0.f; rd = d;
    }
    run += sA[r0l + r][col];
  }
  unsafeAtomicAdd(&agg[(size_t)rd * 64 + col], run);
}

// ====== msg_add (gnn2 iterations): agg += relu(xwm[src] + efwe_sorted[e]) ======
// Pure streaming + register segment-reduce; replaces the per-iteration msg GEMM.
__global__ __launch_bounds__(256) void msg_add(
    const float* __restrict__ xwmR, const float* __restrict__ efweR,
    const int* __restrict__ srcsR, const int* __restrict__ dstsR, float* __restrict__ aggR,
    const float* __restrict__ xwmP, const float* __restrict__ efweP,
    const int* __restrict__ srcsP, const int* __restrict__ dstsP, float* __restrict__ aggP) {
  int lane = threadIdx.x & 63;
  int wv = blockIdx.x * 4 + (threadIdx.x >> 6);   // 0..8191
  bool isP = wv >= 4096;
  const float* xwm = isP ? xwmP : xwmR;
  const float* efwe = isP ? efweP : efweR;
  const int* srcs = isP ? srcsP : srcsR;
  const int* dsts = isP ? dstsP : dstsR;
  float* agg = isP ? aggP : aggR;
  int e0 = (wv & 4095) * 16;
  float run = 0.f;
  int rd = dsts[e0];
#pragma unroll 4
  for (int k = 0; k < 16; ++k) {
    int e = e0 + k;
    int d = dsts[e];
    if (d != rd) {
      unsafeAtomicAdd(&agg[(size_t)rd * 64 + lane], run);
      run = 0.f; rd = d;
    }
    float v = xwm[(size_t)srcs[e] * 64 + lane] + efwe[(size_t)e * 64 + lane];
    run += fmaxf(v, 0.f);
  }
  unsafeAtomicAdd(&agg[(size_t)rd * 64 + lane], run);
}

// ====== node1 dense tiled GEMM: h = relu(X@Ws + agg + b); re-zeroes agg ======
__global__ __launch_bounds__(256) void node1_gemm(
    const float* __restrict__ xR, float* __restrict__ aggR, float* __restrict__ hR,
    const float* __restrict__ xP, float* __restrict__ aggP, float* __restrict__ hP,
    const float* __restrict__ Ws, const float* __restrict__ bias) {
  __shared__ float sX[64][68];
  __shared__ float sW[64][68];
  bool isP = blockIdx.x >= 128;
  const float* x = isP ? xP : xR;
  float* agg = isP ? aggP : aggR;
  float* h = isP ? hP : hR;
  int n0 = (blockIdx.x & 127) * 64;
  int t = threadIdx.x;
#pragma unroll
  for (int idx = 0; idx < 4; ++idx) {
    int q = t * 4 + idx * 1024;
    int k = q >> 6, j = q & 63;
    *reinterpret_cast<float4*>(&sW[k][j]) = *reinterpret_cast<const float4*>(Ws + q);
    float4 v = *reinterpret_cast<const float4*>(x + (size_t)n0 * 64 + q);
    sX[j + 0][k] = v.x; sX[j + 1][k] = v.y; sX[j + 2][k] = v.z; sX[j + 3][k] = v.w;
  }
  __syncthreads();
  int tn = (t & 15) * 4, tj = (t >> 4) * 4;
  float acc[4][4] = {};
#pragma unroll 8
  for (int k = 0; k < 64; ++k) {
    float4 a = *reinterpret_cast<const float4*>(&sX[k][tn]);
    float4 b = *reinterpret_cast<const float4*>(&sW[k][tj]);
    acc[0][0] = fmaf(a.x, b.x, acc[0][0]); acc[0][1] = fmaf(a.x, b.y, acc[0][1]);
    acc[0][2] = fmaf(a.x, b.z, acc[0][2]); acc[0][3] = fmaf(a.x, b.w, acc[0][3]);
    acc[1][0] = fmaf(a.y, b.x, acc[1][0]); acc[1][1] = fmaf(a.y, b.y, acc[1][1]);
    acc[1][2] = fmaf(a.y, b.z, acc[1][2]); acc[1][3] = fmaf(a.y, b.w, acc[1][3]);
    acc[2][0] = fmaf(a.z, b.x, acc[2][0]); acc[2][1] = fmaf(a.z, b.y, acc[2][1]);
    acc[2][2] = fmaf(a.z, b.z, acc[2][2]); acc[2][3] = fmaf(a.z, b.w, acc[2][3]);
    acc[3][0] = fmaf(a.w, b.x, acc[3][0]); acc[3][1] = fmaf(a.w, b.y, acc[3][1]);
    acc[3][2] = fmaf(a.w, b.z, acc[3][2]); acc[3][3] = fmaf(a.w, b.w, acc[3][3]);
  }
  float4 bv = *reinterpret_cast<const float4*>(bias + tj);
  float4 z4 = make_float4(0.f, 0.f, 0.f, 0.f);
#pragma unroll
  for (int i = 0; i < 4; ++i) {
    int n = n0 + tn + i;
    float4 g = *reinterpret_cast<const float4*>(&agg[(size_t)n * 64 + tj]);
    *reinterpret_cast<float4*>(&agg[(size_t)n * 64 + tj]) = z4;
    float4 o;
    o.x = fmaxf(acc[i][0] + g.x + bv.x, 0.f);
    o.y = fmaxf(acc[i][1] + g.y + bv.y, 0.f);
    o.z = fmaxf(acc[i][2] + g.z + bv.z, 0.f);
    o.w = fmaxf(acc[i][3] + g.w + bv.w, 0.f);
    *reinterpret_cast<float4*>(&h[(size_t)n * 64 + tj]) = o;
  }
}

// ====== mhat_soft: Mhat tile + fused row softmax (->Msoft, ->out M0) + it0 RNG ======
__global__ __launch_bounds__(256) void mhat_soft(
    const float* __restrict__ hR, const float* __restrict__ hP,
    float* __restrict__ Mhat, float* __restrict__ Msoft, float* __restrict__ M0out,
    float* __restrict__ rfr, unsigned fk0, unsigned fk1) {
  __shared__ float hr[16][66];
  __shared__ float hp[128][66];
  int gid = blockIdx.x, t = threadIdx.x;
  int gtid = (gid << 8) + t;
#pragma unroll
  for (int q = 0; q < 2; ++q) {
    unsigned i = (unsigned)gtid + (unsigned)q * 131072u;
    unsigned a0 = 0u, a1 = i;
    tf2x32(fk0, fk1, a0, a1);
    rfr[i] = bits_to_normal(a0 ^ a1);
  }
  int b = gid >> 3, r0 = (gid & 7) * 16;
  const float* hrG = hR + ((size_t)(b * 128 + r0)) * 64;
  {
    int q = t * 4; int r = q >> 6, d = q & 63;
    float4 v = *reinterpret_cast<const float4*>(hrG + q);
    hr[r][d] = v.x; hr[r][d + 1] = v.y; hr[r][d + 2] = v.z; hr[r][d + 3] = v.w;
  }
  const float* hpG = hP + (size_t)b * 128 * 64;
#pragma unroll
  for (int rep = 0; rep < 8; ++rep) {
    int q = (rep * 256 + t) * 4; int p = q >> 6, d = q & 63;
    float4 v = *reinterpret_cast<const float4*>(hpG + q);
    hp[p][d] = v.x; hp[p][d + 1] = v.y; hp[p][d + 2] = v.z; hp[p][d + 3] = v.w;
  }
  __syncthreads();
  int tx = t & 31, ty = t >> 5;
  float acc[2][4] = {};
  for (int d = 0; d < 64; ++d) {
    float a0 = hr[ty][d], a1 = hr[ty + 8][d];
    float q0 = hp[tx][d], q1 = hp[tx + 32][d], q2 = hp[tx + 64][d], q3 = hp[tx + 96][d];
    acc[0][0] = fmaf(a0, q0, acc[0][0]); acc[0][1] = fmaf(a0, q1, acc[0][1]);
    acc[0][2] = fmaf(a0, q2, acc[0][2]); acc[0][3] = fmaf(a0, q3, acc[0][3]);
    acc[1][0] = fmaf(a1, q0, acc[1][0]); acc[1][1] = fmaf(a1, q1, acc[1][1]);
    acc[1][2] = fmaf(a1, q2, acc[1][2]); acc[1][3] = fmaf(a1, q3, acc[1][3]);
  }
#pragma unroll
  for (int ii = 0; ii < 2; ++ii) {
    int r = r0 + ty + 8 * ii;
    float* mrow = Mhat + ((size_t)(b * 128 + r)) * 128;
    mrow[tx] = acc[ii][0]; mrow[tx + 32] = acc[ii][1];
    mrow[tx + 64] = acc[ii][2]; mrow[tx + 96] = acc[ii][3];
    float mx = redmax32(fmaxf(fmaxf(acc[ii][0], acc[ii][1]), fmaxf(acc[ii][2], acc[ii][3])));
    float e0 = __expf(acc[ii][0] - mx), e1 = __expf(acc[ii][1] - mx);
    float e2 = __expf(acc[ii][2] - mx), e3 = __expf(acc[ii][3] - mx);
    float inv = 1.0f / redsum32(e0 + e1 + e2 + e3);
    float* srow = Msoft + ((size_t)(b * 128 + r)) * 128;
    srow[tx] = e0 * inv; srow[tx + 32] = e1 * inv;
    srow[tx + 64] = e2 * inv; srow[tx + 96] = e3 * inv;
    float* orow = M0out + ((size_t)(b * 128 + r)) * 128;
    orow[tx] = e0 * inv; orow[tx + 32] = e1 * inv;
    orow[tx + 64] = e2 * inv; orow[tx + 96] = e3 * inv;
  }
}

// ====== rfp + xwm: blocks<512: rfp[b,p,:] = sum_r Msoft[b,r,p]*rfr[b,r,:] and
//        xwm_p = rfp @ Wm2 (in-block).  blocks 512..639: xwm_r = rfr @ Wm2. ======
__global__ __launch_bounds__(256) void rfp_xwm_kern(
    const float* __restrict__ Msoft, const float* __restrict__ rfr,
    float* __restrict__ rfp, const float* __restrict__ Wm2,
    float* __restrict__ xwm_r, float* __restrict__ xwm_p) {
  __shared__ __align__(16) float sm[7232];
  int t = threadIdx.x;
  if (blockIdx.x < 512) {
    float (*rr)[36] = (float(*)[36])sm;            // 128x36
    float (*srow)[36] = (float(*)[36])(sm + 4608); // 16x36
    float (*swm)[64] = (float(*)[64])(sm + 5184);  // 32x64
    int b = blockIdx.x >> 3, p0 = (blockIdx.x & 7) * 16;
    const float* rfG = rfr + (size_t)b * 4096;
#pragma unroll
    for (int rep = 0; rep < 4; ++rep) {
      int q = (rep * 256 + t) * 4; int r = q >> 5, i = q & 31;
      float4 v = *reinterpret_cast<const float4*>(rfG + q);
      rr[r][i] = v.x; rr[r][i + 1] = v.y; rr[r][i + 2] = v.z; rr[r][i + 3] = v.w;
    }
#pragma unroll
    for (int rep = 0; rep < 2; ++rep) {
      int q = t * 4 + rep * 1024;
      *reinterpret_cast<float4*>(&swm[q >> 6][q & 63]) = *reinterpret_cast<const float4*>(Wm2 + q);
    }
    __syncthreads();
    int pl = t & 15, ih = (t >> 4) * 2;
    int p = p0 + pl;
    const float* Mcol = Msoft + (size_t)b * 16384 + p;
    float a0 = 0.f, a1 = 0.f;
#pragma unroll 8
    for (int r = 0; r < 128; ++r) {
      float m = Mcol[(size_t)r * 128];
      a0 = fmaf(m, rr[r][ih], a0);
      a1 = fmaf(m, rr[r][ih + 1], a1);
    }
    float* dst = rfp + ((size_t)(b * 128 + p)) * 32 + ih;
    dst[0] = a0; dst[1] = a1;
    srow[pl][ih] = a0; srow[pl][ih + 1] = a1;
    __syncthreads();
    // xwm_p rows for this block's 16 p's: out[r][c] = sum_k srow[r][k]*swm[k][c]
    int r2 = t & 15, c2 = (t >> 4) * 4;
    float4 av = make_float4(0.f, 0.f, 0.f, 0.f);
#pragma unroll 8
    for (int k = 0; k < 32; ++k) {
      float s = srow[r2][k];
      float4 w = *reinterpret_cast<const float4*>(&swm[k][c2]);
      av.x = fmaf(s, w.x, av.x); av.y = fmaf(s, w.y, av.y);
      av.z = fmaf(s, w.z, av.z); av.w = fmaf(s, w.w, av.w);
    }
    *reinterpret_cast<float4*>(&xwm_p[(size_t)(b * 128 + p0 + r2) * 64 + c2]) = av;
  } else {
    // xwm_r = rfr @ Wm2 : 64-node tiles
    float (*sRF)[68] = (float(*)[68])sm;            // 32x68
    float (*swm)[64] = (float(*)[64])(sm + 2176);   // 32x64
    int n0 = (blockIdx.x - 512) * 64;
#pragma unroll
    for (int rep = 0; rep < 2; ++rep) {
      int q = t * 4 + rep * 1024;
      *reinterpret_cast<float4*>(&swm[q >> 6][q & 63]) = *reinterpret_cast<const float4*>(Wm2 + q);
      int r = q >> 5, kk = q & 31;
      float4 v = *reinterpret_cast<const float4*>(rfr + (size_t)(n0 + r) * 32 + kk);
      sRF[kk][r] = v.x; sRF[kk + 1][r] = v.y; sRF[kk + 2][r] = v.z; sRF[kk + 3][r] = v.w;
    }
    __syncthreads();
    int tn = (t & 15) * 4, tj = (t >> 4) * 4;
    float acc[4][4] = {};
#pragma unroll 8
    for (int k = 0; k < 32; ++k) {
      float4 a = *reinterpret_cast<const float4*>(&sRF[k][tn]);
      float4 b = *reinterpret_cast<const float4*>(&swm[k][tj]);
      acc[0][0] = fmaf(a.x, b.x, acc[0][0]); acc[0][1] = fmaf(a.x, b.y, acc[0][1]);
      acc[0][2] = fmaf(a.x, b.z, acc[0][2]); acc[0][3] = fmaf(a.x, b.w, acc[0][3]);
      acc[1][0] = fmaf(a.y, b.x, acc[1][0]); acc[1][1] = fmaf(a.y, b.y, acc[1][1]);
      acc[1][2] = fmaf(a.y, b.z, acc[1][2]); acc[1][3] = fmaf(a.y, b.w, acc[1][3]);
      acc[2][0] = fmaf(a.z, b.x, acc[2][0]); acc[2][1] = fmaf(a.z, b.y, acc[2][1]);
      acc[2][2] = fmaf(a.z, b.z, acc[2][2]); acc[2][3] = fmaf(a.z, b.w, acc[2][3]);
      acc[3][0] = fmaf(a.w, b.x, acc[3][0]); acc[3][1] = fmaf(a.w, b.y, acc[3][1]);
      acc[3][2] = fmaf(a.w, b.z, acc[3][2]); acc[3][3] = fmaf(a.w, b.w, acc[3][3]);
    }
#pragma unroll
    for (int i = 0; i < 4; ++i) {
      float4 o = make_float4(acc[i][0], acc[i][1], acc[i][2], acc[i][3]);
      *reinterpret_cast<float4*>(&xwm_r[(size_t)(n0 + tn + i) * 64 + tj]) = o;
    }
  }
}

// ====== node2u: o = relu(rf@Ws2 + agg + g2b); u = o@W1 (+b1 for r graph);
//        re-zeroes agg after reading ======
__global__ __launch_bounds__(256) void node2u_gemm(
    const float* __restrict__ rfR, float* __restrict__ aggR, float* __restrict__ uR,
    const float* __restrict__ rfP, float* __restrict__ aggP, float* __restrict__ uP,
    const float* __restrict__ Ws2, const float* __restrict__ g2b,
    const float* __restrict__ W1, const float* __restrict__ b1) {
  __shared__ float sRF[32][68];
  __shared__ float sW2[32][68];
  __shared__ float sW1[64][68];
  __shared__ float sO[64][68];
  bool isP = blockIdx.x >= 128;
  const float* rf = isP ? rfP : rfR;
  float* agg = isP ? aggP : aggR;
  float* u = isP ? uP : uR;
  int n0 = (blockIdx.x & 127) * 64;
  int t = threadIdx.x;
#pragma unroll
  for (int idx = 0; idx < 4; ++idx) {
    int q = t * 4 + idx * 1024;
    *reinterpret_cast<float4*>(&sW1[q >> 6][q & 63]) = *reinterpret_cast<const float4*>(W1 + q);
  }
#pragma unroll
  for (int idx = 0; idx < 2; ++idx) {
    int q = t * 4 + idx * 1024;
    *reinterpret_cast<float4*>(&sW2[q >> 6][q & 63]) = *reinterpret_cast<const float4*>(Ws2 + q);
    int r = q >> 5, kk = q & 31;
    float4 v = *reinterpret_cast<const float4*>(rf + (size_t)(n0 + r) * 32 + kk);
    sRF[kk][r] = v.x; sRF[kk + 1][r] = v.y; sRF[kk + 2][r] = v.z; sRF[kk + 3][r] = v.w;
  }
  __syncthreads();
  int tn = (t & 15) * 4, tj = (t >> 4) * 4;
  float acc[4][4] = {};
#pragma unroll 8
  for (int k = 0; k < 32; ++k) {
    float4 a = *reinterpret_cast<const float4*>(&sRF[k][tn]);
    float4 b = *reinterpret_cast<const float4*>(&sW2[k][tj]);
    acc[0][0] = fmaf(a.x, b.x, acc[0][0]); acc[0][1] = fmaf(a.x, b.y, acc[0][1]);
    acc[0][2] = fmaf(a.x, b.z, acc[0][2]); acc[0][3] = fmaf(a.x, b.w, acc[0][3]);
    acc[1][0] = fmaf(a.y, b.x, acc[1][0]); acc[1][1] = fmaf(a.y, b.y, acc[1][1]);
    acc[1][2] = fmaf(a.y, b.z, acc[1][2]); acc[1][3] = fmaf(a.y, b.w, acc[1][3]);
    acc[2][0] = fmaf(a.z, b.x, acc[2][0]); acc[2][1] = fmaf(a.z, b.y, acc[2][1]);
    acc[2][2] = fmaf(a.z, b.z, acc[2][2]); acc[2][3] = fmaf(a.z, b.w, acc[2][3]);
    acc[3][0] = fmaf(a.w, b.x, acc[3][0]); acc[3][1] = fmaf(a.w, b.y, acc[3][1]);
    acc[3][2] = fmaf(a.w, b.z, acc[3][2]); acc[3][3] = fmaf(a.w, b.w, acc[3][3]);
  }
  float4 bg = *reinterpret_cast<const float4*>(g2b + tj);
  float4 z4 = make_float4(0.f, 0.f, 0.f, 0.f);
#pragma unroll
  for (int i = 0; i < 4; ++i) {
    int n = n0 + tn + i;
    float4 g = *reinterpret_cast<const float4*>(&agg[(size_t)n * 64 + tj]);
    *reinterpret_cast<float4*>(&agg[(size_t)n * 64 + tj]) = z4;
    sO[tj + 0][tn + i] = fmaxf(acc[i][0] + g.x + bg.x, 0.f);
    sO[tj + 1][tn + i] = fmaxf(acc[i][1] + g.y + bg.y, 0.f);
    sO[tj + 2][tn + i] = fmaxf(acc[i][2] + g.z + bg.z, 0.f);
    sO[tj + 3][tn + i] = fmaxf(acc[i][3] + g.w + bg.w, 0.f);
  }
  __syncthreads();
  float acc2[4][4] = {};
#pragma unroll 8
  for (int k = 0; k < 64; ++k) {
    float4 a = *reinterpret_cast<const float4*>(&sO[k][tn]);
    float4 b = *reinterpret_cast<const float4*>(&sW1[k][tj]);
    acc2[0][0] = fmaf(a.x, b.x, acc2[0][0]); acc2[0][1] = fmaf(a.x, b.y, acc2[0][1]);
    acc2[0][2] = fmaf(a.x, b.z, acc2[0][2]); acc2[0][3] = fmaf(a.x, b.w, acc2[0][3]);
    acc2[1][0] = fmaf(a.y, b.x, acc2[1][0]); acc2[1][1] = fmaf(a.y, b.y, acc2[1][1]);
    acc2[1][2] = fmaf(a.y, b.z, acc2[1][2]); acc2[1][3] = fmaf(a.y, b.w, acc2[1][3]);
    acc2[2][0] = fmaf(a.z, b.x, acc2[2][0]); acc2[2][1] = fmaf(a.z, b.y, acc2[2][1]);
    acc2[2][2] = fmaf(a.z, b.z, acc2[2][2]); acc2[2][3] = fmaf(a.z, b.w, acc2[2][3]);
    acc2[3][0] = fmaf(a.w, b.x, acc2[3][0]); acc2[3][1] = fmaf(a.w, b.y, acc2[3][1]);
    acc2[3][2] = fmaf(a.w, b.z, acc2[3][2]); acc2[3][3] = fmaf(a.w, b.w, acc2[3][3]);
  }
  float4 b1v = make_float4(0.f, 0.f, 0.f, 0.f);
  if (!isP) b1v = *reinterpret_cast<const float4*>(b1 + tj);
#pragma unroll
  for (int i = 0; i < 4; ++i) {
    int n = n0 + tn + i;
    float4 o;
    o.x = acc2[i][0] + b1v.x; o.y = acc2[i][1] + b1v.y;
    o.z = acc2[i][2] + b1v.z; o.w = acc2[i][3] + b1v.w;
    *reinterpret_cast<float4*>(&u[(size_t)n * 64 + tj]) = o;
  }
}

// ====== upd_soft: Mhat += pairwise MLP; fused row softmax -> (Msoft | final out);
//        optional RNG for next iteration. 512 blocks. ======
__global__ __launch_bounds__(256) void upd_soft(
    const float* __restrict__ uR, const float* __restrict__ uP,
    const float* __restrict__ W2, const float* __restrict__ b2p,
    float* __restrict__ Mhat, float* __restrict__ softDst,
    int writeMhat, float* __restrict__ rfr, int doRng,
    unsigned fk0, unsigned fk1) {
  __shared__ float sur[16][66];
  __shared__ float sup[128][66];
  __shared__ float sw2[64];
  int gid = blockIdx.x, t = threadIdx.x;
  int b = gid >> 3, r0 = (gid & 7) * 16;
  const float* urG = uR + ((size_t)(b * 128 + r0)) * 64;
  {
    int q = t * 4; int r = q >> 6, d = q & 63;
    float4 v = *reinterpret_cast<const float4*>(urG + q);
    sur[r][d] = v.x; sur[r][d + 1] = v.y; sur[r][d + 2] = v.z; sur[r][d + 3] = v.w;
  }
  const float* upG = uP + (size_t)b * 128 * 64;
#pragma unroll
  for (int rep = 0; rep < 8; ++rep) {
    int q = (rep * 256 + t) * 4; int p = q >> 6, d = q & 63;
    float4 v = *reinterpret_cast<const float4*>(upG + q);
    sup[p][d] = v.x; sup[p][d + 1] = v.y; sup[p][d + 2] = v.z; sup[p][d + 3] = v.w;
  }
  if (t < 64) sw2[t] = W2[t];
  __syncthreads();
  int tx = t & 31, ty = t >> 5;
  float acc[2][4] = {};
  for (int j = 0; j < 64; ++j) {
    float w2v = sw2[j];
    float a0 = sur[ty][j], a1 = sur[ty + 8][j];
    float q0 = sup[tx][j], q1 = sup[tx + 32][j], q2 = sup[tx + 64][j], q3 = sup[tx + 96][j];
    acc[0][0] = fmaf(fmaxf(a0 - q0, 0.f), w2v, acc[0][0]);
    acc[0][1] = fmaf(fmaxf(a0 - q1, 0.f), w2v, acc[0][1]);
    acc[0][2] = fmaf(fmaxf(a0 - q2, 0.f), w2v, acc[0][2]);
    acc[0][3] = fmaf(fmaxf(a0 - q3, 0.f), w2v, acc[0][3]);
    acc[1][0] = fmaf(fmaxf(a1 - q0, 0.f), w2v, acc[1][0]);
    acc[1][1] = fmaf(fmaxf(a1 - q1, 0.f), w2v, acc[1][1]);
    acc[1][2] = fmaf(fmaxf(a1 - q2, 0.f), w2v, acc[1][2]);
    acc[1][3] = fmaf(fmaxf(a1 - q3, 0.f), w2v, acc[1][3]);
  }
  float b2v = b2p[0];
#pragma unroll
  for (int ii = 0; ii < 2; ++ii) {
    int r = r0 + ty + 8 * ii;
    float* mrow = Mhat + ((size_t)(b * 128 + r)) * 128;
    float m0 = mrow[tx] + acc[ii][0] + b2v;
    float m1 = mrow[tx + 32] + acc[ii][1] + b2v;
    float m2 = mrow[tx + 64] + acc[ii][2] + b2v;
    float m3 = mrow[tx + 96] + acc[ii][3] + b2v;
    if (writeMhat) {
      mrow[tx] = m0; mrow[tx + 32] = m1; mrow[tx + 64] = m2; mrow[tx + 96] = m3;
    }
    float mx = redmax32(fmaxf(fmaxf(m0, m1), fmaxf(m2, m3)));
    float e0 = __expf(m0 - mx), e1 = __expf(m1 - mx);
    float e2 = __expf(m2 - mx), e3 = __expf(m3 - mx);
    float inv = 1.0f / redsum32(e0 + e1 + e2 + e3);
    float* srow = softDst + ((size_t)(b * 128 + r)) * 128;
    srow[tx] = e0 * inv; srow[tx + 32] = e1 * inv;
    srow[tx + 64] = e2 * inv; srow[tx + 96] = e3 * inv;
  }
  if (doRng) {
    int gtid = (gid << 8) + t;
#pragma unroll
    for (int q = 0; q < 2; ++q) {
      unsigned i = (unsigned)gtid + (unsigned)q * 131072u;
      unsigned a0 = 0u, a1 = i;
      tf2x32(fk0, fk1, a0, a1);
      rfr[i] = bits_to_normal(a0 ^ a1);
    }
  }
}

extern "C" void kernel_launch(void* const* d_in, const int* in_sizes, int n_in,
                              void* d_out, int out_size, void* d_ws, size_t ws_size,
                              hipStream_t stream) {
  (void)in_sizes; (void)n_in; (void)out_size; (void)ws_size;
  const float* x_r  = (const float*)d_in[0];
  const int*   ei_r = (const int*)d_in[1];
  const float* ef_r = (const float*)d_in[2];
  const float* x_p  = (const float*)d_in[3];
  const int*   ei_p = (const int*)d_in[4];
  const float* ef_p = (const float*)d_in[5];
  const float* g1_Ws = (const float*)d_in[8];
  const float* g1_Wm = (const float*)d_in[9];
  const float* g1_We = (const float*)d_in[10];
  const float* g1_b  = (const float*)d_in[11];
  const float* g2_Ws = (const float*)d_in[12];
  const float* g2_Wm = (const float*)d_in[13];
  const float* g2_We = (const float*)d_in[14];
  const float* g2_b  = (const float*)d_in[15];
  const float* W1 = (const float*)d_in[16];
  const float* b1 = (const float*)d_in[17];
  const float* W2 = (const float*)d_in[18];
  const float* b2 = (const float*)d_in[19];
  float* out = (float*)d_out;

  float* ws = (float*)d_ws;
  float* h_r   = ws;                 // 524288
  float* h_p   = h_r + 524288;       // 524288
  float* Mhat  = h_p + 524288;       // 1048576
  float* Msoft = Mhat + 1048576;     // 1048576
  float* rfr   = Msoft + 1048576;    // 262144
  float* rfp   = rfr + 262144;       // 262144
  float* u_r   = rfp + 262144;       // 524288 (aliased as xwm_r during msg_add window)
  float* u_p   = u_r + 524288;       // 524288 (aliased as xwm_p)
  float* agg_r = u_p + 524288;       // 524288
  float* agg_p = agg_r + 524288;     // 524288 (contiguous with agg_r for zeroing)
  float* efwe_r = agg_p + 524288;    // 4194304
  float* efwe_p = efwe_r + 4194304;  // 4194304
  int* ib      = (int*)(efwe_p + 4194304);
  int* off_r  = ib;                  // 8192 (zeroed; hist counts -> scan offsets)
  int* off_p  = off_r + 8192;        // 8192
  int* perm_r = off_p + 8192;        // 65536
  int* perm_p = perm_r + 65536;      // 65536
  int* srcs_r = perm_p + 65536;      // 65536
  int* srcs_p = srcs_r + 65536;      // 65536
  int* dsts_r = srcs_p + 65536;      // 65536
  int* dsts_p = dsts_r + 65536;      // 65536
  float* xwm_r = u_r;                // alias: dead window of u
  float* xwm_p = u_p;

  // folded keys for the 3 iterations (host-side, deterministic)
  unsigned fk0[3], fk1[3];
  for (int it = 0; it < 3; ++it) {
    unsigned a = 0u, c = (unsigned)it;
    tf2x32(0u, 42u, a, c);
    fk0[it] = a; fk1[it] = c;
  }

  // ---- CSR build + agg zeroing ----
  hipMemsetAsync(off_r, 0, 2 * 8192 * sizeof(int), stream);
  hist_kern<<<512, 256, 0, stream>>>(ei_r, ei_p, off_r, off_p, agg_r);
  scan_kern<<<2, 256, 0, stream>>>(off_r, off_p);
  scatter_kern<<<512, 256, 0, stream>>>(ei_r, ei_p, off_r, off_p,
                                        perm_r, perm_p, srcs_r, srcs_p,
                                        dsts_r, dsts_p);

  // ---- gnn1 msg GEMM (+agg atomics) and one-time efwe = ef@We2 precompute ----
  msg_gemm<64><<<4096, 256, 0, stream>>>(x_r, ef_r, srcs_r, perm_r, dsts_r, agg_r,
                                         x_p, ef_p, srcs_p, perm_p, dsts_p, agg_p,
                                         g1_Wm, g1_We, g2_We, efwe_r, efwe_p);
  node1_gemm<<<256, 256, 0, stream>>>(x_r, agg_r, h_r, x_p, agg_p, h_p, g1_Ws, g1_b);
  mhat_soft<<<512, 256, 0, stream>>>(h_r, h_p, Mhat, Msoft, out, rfr, fk0[0], fk1[0]);

  for (int it = 0; it < 3; ++it) {
    rfp_xwm_kern<<<640, 256, 0, stream>>>(Msoft, rfr, rfp, g2_Wm, xwm_r, xwm_p);
    msg_add<<<2048, 256, 0, stream>>>(xwm_r, efwe_r, srcs_r, dsts_r, agg_r,
                                      xwm_p, efwe_p, srcs_p, dsts_p, agg_p);
    node2u_gemm<<<256, 256, 0, stream>>>(rfr, agg_r, u_r, rfp, agg_p, u_p,
                                         g2_Ws, g2_b, W1, b1);
    int last = (it == 2);
    upd_soft<<<512, 256, 0, stream>>>(u_r, u_p, W2, b2, Mhat,
                                      last ? (out + 1048576) : Msoft,
                                      /*writeMhat=*/!last,
                                      rfr, /*doRng=*/!last,
                                      fk0[it < 2 ? it + 1 : 0], fk1[it < 2 ? it + 1 : 0]);
  }
}